// Round 2
// baseline (7522.516 us; speedup 1.0000x reference)
//
#include <hip/hip_runtime.h>
#include <stdint.h>

#define NPTS  2048
#define BATCH 2
#define KNN   128
#define C1    128
#define C2    256
#define C3    512
#define C4    128
#define JC    16
#define NCHUNK (KNN / JC)      // 8
#define NGROUP (BATCH * NPTS)  // 4096
#define FEAT_ELEMS (BATCH * C4 * NPTS)  // 524288

// ---------------------------------------------------------------------------
// Weight pre-transpose so GEMM inner loops read coalesced columns.
// w2 [C2][C1] -> w2t[c1*C2 + c2] ; w3 [C3][C3] -> w3t[c*C3 + r] ; w4 [C4][C3] -> w4t[c*C4 + c4]
__global__ void prep_kernel(const float* __restrict__ w2, const float* __restrict__ w3,
                            const float* __restrict__ w4,
                            float* __restrict__ w2t, float* __restrict__ w3t,
                            float* __restrict__ w4t) {
    int tid = blockIdx.x * blockDim.x + threadIdx.x;
    int stride = gridDim.x * blockDim.x;
    for (int i = tid; i < C2 * C1; i += stride) w2t[(i & (C1 - 1)) * C2 + (i >> 7)] = w2[i];
    for (int i = tid; i < C3 * C3; i += stride) w3t[(i & (C3 - 1)) * C3 + (i >> 9)] = w3[i];
    for (int i = tid; i < C4 * C3; i += stride) w4t[(i & (C3 - 1)) * C4 + (i >> 9)] = w4[i];
}

// ---------------------------------------------------------------------------
// K0: exact kNN (tie-break by index, matching stable top_k on -sqrt(max(d2,0)))
//     + grouped relative positions + BN1 moment accumulation.
// Distance arithmetic replicates the reference bit-for-bit:
//   sq   = (x*x + y*y) + z*z        (separate mul + sequential add, NO fma)
//   dot  = fma(z,z', fma(y,y', x*x'))  (Eigen/BLAS k-ascending FMA chain)
//   d2   = (sq_i + sq_j) - 2*dot
//   dist = sqrtf(max(d2, 0))        (HIP default sqrtf = correctly rounded)
__launch_bounds__(256)
__global__ void knn_kernel(const float* __restrict__ pos,
                           const float* __restrict__ w1, const float* __restrict__ b1,
                           float* __restrict__ out,   // idx written at out + FEAT_ELEMS
                           float* __restrict__ gp,
                           float* __restrict__ bn1sum, float* __restrict__ bn1sq) {
    __shared__ float px[NPTS], py[NPTS], pz[NPTS];
    __shared__ unsigned long long keys[NPTS];
    __shared__ float gsx[KNN], gsy[KNN], gsz[KNN];
    __shared__ float red[256];

    int t = threadIdx.x;
    int blk = blockIdx.x;              // group = b*NPTS + n
    int b = blk >> 11, n = blk & (NPTS - 1);
    const float* pb = pos + (size_t)b * NPTS * 3;
    for (int i = t; i < NPTS; i += 256) {
        px[i] = pb[i * 3 + 0]; py[i] = pb[i * 3 + 1]; pz[i] = pb[i * 3 + 2];
    }
    __syncthreads();
    float qx = px[n], qy = py[n], qz = pz[n];
    {
        #pragma clang fp contract(off)
        float sqi = (qx * qx + qy * qy) + qz * qz;
        for (int j = t; j < NPTS; j += 256) {
            float xj = px[j], yj = py[j], zj = pz[j];
            float sqj = (xj * xj + yj * yj) + zj * zj;
            float dot = fmaf(qz, zj, fmaf(qy, yj, qx * xj));   // k-ascending FMA chain
            float d2 = (sqi + sqj) - 2.0f * dot;
            float dist = sqrtf(fmaxf(d2, 0.0f));
            unsigned int bits = __float_as_uint(dist);   // dist >= +0 -> monotone as uint
            keys[j] = ((unsigned long long)bits << 32) | (unsigned int)j;
        }
    }
    __syncthreads();
    // bitonic sort ascending over (dist, idx)
    for (int k2 = 2; k2 <= NPTS; k2 <<= 1) {
        for (int s = k2 >> 1; s > 0; s >>= 1) {
            for (int i = t; i < NPTS; i += 256) {
                int l = i ^ s;
                if (l > i) {
                    unsigned long long a = keys[i], c = keys[l];
                    bool up = ((i & k2) == 0);
                    if ((a > c) == up) { keys[i] = c; keys[l] = a; }
                }
            }
            __syncthreads();
        }
    }
    if (t < KNN) {
        unsigned int j = (unsigned int)(keys[t] & 0xffffffffu);
        out[FEAT_ELEMS + (size_t)blk * KNN + t] = (float)j;   // idx as float32 value
        float gx_ = px[j] - qx, gy_ = py[j] - qy, gz_ = pz[j] - qz;
        gsx[t] = gx_; gsy[t] = gy_; gsz[t] = gz_;
        float* g = gp + ((size_t)blk * KNN + t) * 3;
        g[0] = gx_; g[1] = gy_; g[2] = gz_;
    }
    __syncthreads();
    // BN1 moments of f1 = w1*gp + b1 over this group's 128 neighbors
    int c = t & (C1 - 1);
    int half = t >> 7;
    float wa = w1[c * 3 + 0], wb = w1[c * 3 + 1], wc = w1[c * 3 + 2], bc = b1[c];
    float s = 0.f, q = 0.f;
    for (int r = half * 64; r < half * 64 + 64; ++r) {
        float f = wa * gsx[r] + wb * gsy[r] + wc * gsz[r] + bc;
        s += f; q += f * f;
    }
    red[t] = s; __syncthreads();
    if (t < C1) atomicAdd(bn1sum + t, red[t] + red[t + C1]);
    __syncthreads();
    red[t] = q; __syncthreads();
    if (t < C1) atomicAdd(bn1sq + t, red[t] + red[t + C1]);
}

// ---------------------------------------------------------------------------
__global__ void bn_finalize(const float* __restrict__ sum, const float* __restrict__ sq,
                            const float* __restrict__ g, const float* __restrict__ be,
                            float* __restrict__ scale, float* __restrict__ shift,
                            int nch, float inv_count) {
    int c = blockIdx.x * blockDim.x + threadIdx.x;
    if (c < nch) {
        float m = sum[c] * inv_count;
        float v = fmaxf(sq[c] * inv_count - m * m, 0.f);
        float sc = g[c] / sqrtf(v + 1e-5f);
        scale[c] = sc;
        shift[c] = be[c] - m * sc;
    }
}

// ---------------------------------------------------------------------------
// K2: conv1->BN1->ReLU->conv2 -> fg=max_j ; conv3 partial m[r][j] (cols 256..511);
//     BN2 moments via f3 = m + c3(fg) decomposition. Stores fg.
__launch_bounds__(256)
__global__ void stats2_kernel(const float* __restrict__ gp,
                              const float* __restrict__ w1, const float* __restrict__ b1,
                              const float* __restrict__ sc1, const float* __restrict__ sh1,
                              const float* __restrict__ w2t, const float* __restrict__ b2,
                              const float* __restrict__ w3t, const float* __restrict__ b3,
                              float* __restrict__ fgout,
                              float* __restrict__ bn2sum, float* __restrict__ bn2sq) {
    __shared__ float gx[KNN], gy[KNN], gz[KNN];
    __shared__ float w1s[C1 * 3], b1s[C1], sc1s[C1], sh1s[C1];
    __shared__ float h1[C1][JC + 1];
    __shared__ float f2s[C2][JC + 1];
    __shared__ float fgs[C2];
    int t = threadIdx.x, blk = blockIdx.x;
    const float* g = gp + (size_t)blk * KNN * 3;
    for (int i = t; i < KNN; i += 256) { gx[i] = g[i*3]; gy[i] = g[i*3+1]; gz[i] = g[i*3+2]; }
    for (int i = t; i < C1 * 3; i += 256) w1s[i] = w1[i];
    if (t < C1) { b1s[t] = b1[t]; sc1s[t] = sc1[t]; sh1s[t] = sh1[t]; }
    fgs[t] = -3.4e38f;
    __syncthreads();

    float m1 = 0.f, m2 = 0.f, q1 = 0.f, q2 = 0.f;   // rows t and t+256 running moments of m
    for (int ch = 0; ch < NCHUNK; ++ch) {
        int j0 = ch * JC;
        for (int e = t; e < C1 * JC; e += 256) {
            int cc = e >> 4, j = e & (JC - 1);
            float f = w1s[cc*3] * gx[j0+j] + w1s[cc*3+1] * gy[j0+j] + w1s[cc*3+2] * gz[j0+j] + b1s[cc];
            h1[cc][j] = fmaxf(f * sc1s[cc] + sh1s[cc], 0.f);
        }
        __syncthreads();
        // conv2: this thread owns output channel c2 = t
        float acc[JC];
        #pragma unroll
        for (int j = 0; j < JC; ++j) acc[j] = 0.f;
        for (int c1_ = 0; c1_ < C1; ++c1_) {
            float w = w2t[c1_ * C2 + t];
            #pragma unroll
            for (int j = 0; j < JC; ++j) acc[j] += w * h1[c1_][j];
        }
        float bb = b2[t];
        float mx = -3.4e38f;
        #pragma unroll
        for (int j = 0; j < JC; ++j) { float v = acc[j] + bb; f2s[t][j] = v; mx = fmaxf(mx, v); }
        fgs[t] = fmaxf(fgs[t], mx);
        __syncthreads();
        // conv3 partial over f2 (input channels 256..511), rows t and t+256
        float a0[JC], a1[JC];
        #pragma unroll
        for (int j = 0; j < JC; ++j) { a0[j] = 0.f; a1[j] = 0.f; }
        for (int c2_ = 0; c2_ < C2; ++c2_) {
            const float* wr = w3t + (size_t)(C2 + c2_) * C3;
            float wA = wr[t], wB = wr[t + 256];
            #pragma unroll
            for (int j = 0; j < JC; ++j) { float f = f2s[c2_][j]; a0[j] += wA * f; a1[j] += wB * f; }
        }
        #pragma unroll
        for (int j = 0; j < JC; ++j) {
            m1 += a0[j]; q1 += a0[j] * a0[j];
            m2 += a1[j]; q2 += a1[j] * a1[j];
        }
        __syncthreads();
    }
    // c3 rows (fg-broadcast half of conv3, includes b3)
    float c3a = b3[t], c3b = b3[t + 256];
    for (int c2_ = 0; c2_ < C2; ++c2_) {
        float f = fgs[c2_];
        c3a += w3t[(size_t)c2_ * C3 + t] * f;
        c3b += w3t[(size_t)c2_ * C3 + t + 256] * f;
    }
    // f3 = m + C  ->  sum = S1 + 128*C ; sumsq = S2 + 2*C*S1 + 128*C^2
    atomicAdd(bn2sum + t,        m1 + 128.f * c3a);
    atomicAdd(bn2sq  + t,        q1 + 2.f * c3a * m1 + 128.f * c3a * c3a);
    atomicAdd(bn2sum + t + 256,  m2 + 128.f * c3b);
    atomicAdd(bn2sq  + t + 256,  q2 + 2.f * c3b * m2 + 128.f * c3b * c3b);
    fgout[(size_t)blk * C2 + t] = fgs[t];
}

// ---------------------------------------------------------------------------
// K3: recompute pipeline, apply BN2+ReLU, conv4, max over k -> feat
__launch_bounds__(256)
__global__ void final_kernel(const float* __restrict__ gp,
                             const float* __restrict__ w1, const float* __restrict__ b1,
                             const float* __restrict__ sc1, const float* __restrict__ sh1,
                             const float* __restrict__ w2t, const float* __restrict__ b2,
                             const float* __restrict__ w3t, const float* __restrict__ b3,
                             const float* __restrict__ sc2, const float* __restrict__ sh2,
                             const float* __restrict__ w4t, const float* __restrict__ b4,
                             const float* __restrict__ fgin, float* __restrict__ out) {
    __shared__ float gx[KNN], gy[KNN], gz[KNN];
    __shared__ float w1s[C1 * 3], b1s[C1], sc1s[C1], sh1s[C1];
    __shared__ float sc2s[C3], sh2s[C3], c3s[C3];
    __shared__ float fgs[C2];                 // reused as feat-reduce buffer at the end
    __shared__ float f2s[C2][JC + 1];
    __shared__ float g3[C3][JC + 1];          // rows [0..C1) double as h1 within a chunk
    float (*h1)[JC + 1] = (float (*)[JC + 1])g3;

    int t = threadIdx.x, blk = blockIdx.x;
    const float* g = gp + (size_t)blk * KNN * 3;
    for (int i = t; i < KNN; i += 256) { gx[i] = g[i*3]; gy[i] = g[i*3+1]; gz[i] = g[i*3+2]; }
    for (int i = t; i < C1 * 3; i += 256) w1s[i] = w1[i];
    if (t < C1) { b1s[t] = b1[t]; sc1s[t] = sc1[t]; sh1s[t] = sh1[t]; }
    for (int i = t; i < C3; i += 256) { sc2s[i] = sc2[i]; sh2s[i] = sh2[i]; }
    fgs[t] = fgin[(size_t)blk * C2 + t];
    __syncthreads();
    // c3 rows (includes b3)
    {
        float c3a = b3[t], c3b = b3[t + 256];
        for (int c2_ = 0; c2_ < C2; ++c2_) {
            float f = fgs[c2_];
            c3a += w3t[(size_t)c2_ * C3 + t] * f;
            c3b += w3t[(size_t)c2_ * C3 + t + 256] * f;
        }
        c3s[t] = c3a; c3s[t + 256] = c3b;
    }
    __syncthreads();

    int c4 = t & (C4 - 1), jh = t >> 7;
    float fm = -3.4e38f;
    for (int ch = 0; ch < NCHUNK; ++ch) {
        int j0 = ch * JC;
        for (int e = t; e < C1 * JC; e += 256) {
            int cc = e >> 4, j = e & (JC - 1);
            float f = w1s[cc*3] * gx[j0+j] + w1s[cc*3+1] * gy[j0+j] + w1s[cc*3+2] * gz[j0+j] + b1s[cc];
            h1[cc][j] = fmaxf(f * sc1s[cc] + sh1s[cc], 0.f);
        }
        __syncthreads();
        // conv2
        float acc[JC];
        #pragma unroll
        for (int j = 0; j < JC; ++j) acc[j] = 0.f;
        for (int c1_ = 0; c1_ < C1; ++c1_) {
            float w = w2t[c1_ * C2 + t];
            #pragma unroll
            for (int j = 0; j < JC; ++j) acc[j] += w * h1[c1_][j];
        }
        float bb = b2[t];
        #pragma unroll
        for (int j = 0; j < JC; ++j) f2s[t][j] = acc[j] + bb;
        __syncthreads();
        // conv3 + BN2 + ReLU -> g3
        float a0[JC], a1[JC];
        #pragma unroll
        for (int j = 0; j < JC; ++j) { a0[j] = 0.f; a1[j] = 0.f; }
        for (int c2_ = 0; c2_ < C2; ++c2_) {
            const float* wr = w3t + (size_t)(C2 + c2_) * C3;
            float wA = wr[t], wB = wr[t + 256];
            #pragma unroll
            for (int j = 0; j < JC; ++j) { float f = f2s[c2_][j]; a0[j] += wA * f; a1[j] += wB * f; }
        }
        float sA = sc2s[t], hA = sh2s[t], cA = c3s[t];
        float sB = sc2s[t + 256], hB = sh2s[t + 256], cB = c3s[t + 256];
        #pragma unroll
        for (int j = 0; j < JC; ++j) {
            g3[t][j]       = fmaxf((a0[j] + cA) * sA + hA, 0.f);
            g3[t + 256][j] = fmaxf((a1[j] + cB) * sB + hB, 0.f);
        }
        __syncthreads();
        // conv4 on this chunk; thread handles (c4, 8 j's)
        float f4[8];
        #pragma unroll
        for (int jj = 0; jj < 8; ++jj) f4[jj] = 0.f;
        for (int cc = 0; cc < C3; ++cc) {
            float w = w4t[cc * C4 + c4];
            #pragma unroll
            for (int jj = 0; jj < 8; ++jj) f4[jj] += w * g3[cc][jh * 8 + jj];
        }
        #pragma unroll
        for (int jj = 0; jj < 8; ++jj) fm = fmaxf(fm, f4[jj]);
        __syncthreads();
    }
    fgs[t] = fm;
    __syncthreads();
    if (t < C4) {
        float v = fmaxf(fgs[t], fgs[t + C4]) + b4[t];
        int b = blk >> 11, n = blk & (NPTS - 1);
        out[((size_t)b * C4 + t) * NPTS + n] = v;
    }
}

// ---------------------------------------------------------------------------
extern "C" void kernel_launch(void* const* d_in, const int* in_sizes, int n_in,
                              void* d_out, int out_size, void* d_ws, size_t ws_size,
                              hipStream_t stream) {
    const float* pos = (const float*)d_in[0];
    const float* w1  = (const float*)d_in[1];
    const float* b1  = (const float*)d_in[2];
    const float* g1  = (const float*)d_in[3];
    const float* be1 = (const float*)d_in[4];
    const float* w2  = (const float*)d_in[5];
    const float* b2  = (const float*)d_in[6];
    const float* w3  = (const float*)d_in[7];
    const float* b3  = (const float*)d_in[8];
    const float* g2  = (const float*)d_in[9];
    const float* be2 = (const float*)d_in[10];
    const float* w4  = (const float*)d_in[11];
    const float* b4  = (const float*)d_in[12];
    float* out = (float*)d_out;
    float* ws  = (float*)d_ws;

    float* gp     = ws;                         // 4096*128*3 = 1572864
    float* w2t    = gp + 1572864;               // 32768
    float* w3t    = w2t + 32768;                // 262144
    float* w4t    = w3t + 262144;               // 65536
    float* bn1sum = w4t + 65536;                // 128
    float* bn1sq  = bn1sum + 128;               // 128
    float* bn2sum = bn1sq + 128;                // 512
    float* bn2sq  = bn2sum + 512;               // 512
    float* sc1    = bn2sq + 512;                // 128
    float* sh1    = sc1 + 128;                  // 128
    float* sc2    = sh1 + 128;                  // 512
    float* sh2    = sc2 + 512;                  // 512
    float* fg     = sh2 + 512;                  // 4096*256 = 1048576

    hipMemsetAsync(bn1sum, 0, 1280 * sizeof(float), stream);   // zero all 4 stat buffers
    prep_kernel<<<512, 256, 0, stream>>>(w2, w3, w4, w2t, w3t, w4t);
    knn_kernel<<<NGROUP, 256, 0, stream>>>(pos, w1, b1, out, gp, bn1sum, bn1sq);
    bn_finalize<<<1, 128, 0, stream>>>(bn1sum, bn1sq, g1, be1, sc1, sh1, C1, 1.f / 524288.f);
    stats2_kernel<<<NGROUP, 256, 0, stream>>>(gp, w1, b1, sc1, sh1, w2t, b2, w3t, b3,
                                              fg, bn2sum, bn2sq);
    bn_finalize<<<1, 512, 0, stream>>>(bn2sum, bn2sq, g2, be2, sc2, sh2, C3, 1.f / 524288.f);
    final_kernel<<<NGROUP, 256, 0, stream>>>(gp, w1, b1, sc1, sh1, w2t, b2, w3t, b3,
                                             sc2, sh2, w4t, b4, fg, out);
}

// Round 3
// 5705.668 us; speedup vs baseline: 1.3184x; 1.3184x over previous
//
#include <hip/hip_runtime.h>
#include <stdint.h>

#define NPTS  2048
#define BATCH 2
#define KNN   128
#define C1    128
#define C2    256
#define C3    512
#define C4    128
#define JC    16
#define PAD   20                 // row stride (floats): 16B-aligned, non-pow2 banks
#define NCHUNK (KNN / JC)        // 8
#define NGROUP (BATCH * NPTS)    // 4096
#define FEAT_ELEMS (BATCH * C4 * NPTS)  // 524288
#define HBINS 2048
#define NREP  8                  // atomic replication factor

// ---------------------------------------------------------------------------
__global__ void prep_kernel(const float* __restrict__ w2, const float* __restrict__ w3,
                            const float* __restrict__ w4,
                            float* __restrict__ w2t, float* __restrict__ w3t,
                            float* __restrict__ w4t) {
    int tid = blockIdx.x * blockDim.x + threadIdx.x;
    int stride = gridDim.x * blockDim.x;
    for (int i = tid; i < C2 * C1; i += stride) w2t[(i & (C1 - 1)) * C2 + (i >> 7)] = w2[i];
    for (int i = tid; i < C3 * C3; i += stride) w3t[(i & (C3 - 1)) * C3 + (i >> 9)] = w3[i];
    for (int i = tid; i < C4 * C3; i += stride) w4t[(i & (C3 - 1)) * C4 + (i >> 9)] = w4[i];
}

// ---------------------------------------------------------------------------
// K0: exact kNN via 2-level radix select on distance bits + bitonic-256 of
// candidates. Distance arithmetic bit-identical to the reference:
//   sq = (x*x + y*y) + z*z (no fma); dot = fma chain k-ascending;
//   d2 = (sq_i+sq_j) - 2*dot; dist = sqrtf(max(d2,0)).
__launch_bounds__(256)
__global__ void knn_kernel(const float* __restrict__ pos,
                           const float* __restrict__ w1, const float* __restrict__ b1,
                           float* __restrict__ out,
                           float* __restrict__ gp,
                           float* __restrict__ bn1sumr, float* __restrict__ bn1sqr) {
    __shared__ float px[NPTS], py[NPTS], pz[NPTS];
    __shared__ unsigned int dbits[NPTS];
    __shared__ unsigned int hist[HBINS];
    __shared__ unsigned int seg[256];
    __shared__ unsigned long long cand[256];
    __shared__ float gsx[KNN], gsy[KNN], gsz[KNN];
    __shared__ float red[256];
    __shared__ unsigned int s_b1, s_c0, s_p22, s_cnt;

    int t = threadIdx.x;
    int blk = blockIdx.x;
    int b = blk >> 11, n = blk & (NPTS - 1);
    const float* pb = pos + (size_t)b * NPTS * 3;
    for (int i = t; i < NPTS; i += 256) {
        px[i] = pb[i * 3 + 0]; py[i] = pb[i * 3 + 1]; pz[i] = pb[i * 3 + 2];
    }
    for (int i = t; i < HBINS; i += 256) hist[i] = 0;
    if (t == 0) s_cnt = 0;
    __syncthreads();

    float qx = px[n], qy = py[n], qz = pz[n];
    {
        #pragma clang fp contract(off)
        float sqi = (qx * qx + qy * qy) + qz * qz;
        for (int j = t; j < NPTS; j += 256) {
            float xj = px[j], yj = py[j], zj = pz[j];
            float sqj = (xj * xj + yj * yj) + zj * zj;
            float dot = fmaf(qz, zj, fmaf(qy, yj, qx * xj));
            float d2 = (sqi + sqj) - 2.0f * dot;
            float dist = sqrtf(fmaxf(d2, 0.0f));
            unsigned int bits = __float_as_uint(dist);
            dbits[j] = bits;
            atomicAdd(&hist[bits >> 20], 1u);     // pass-1 bin: bits[31:20]
        }
    }
    __syncthreads();

    // ---- pass 1: find bin B1 containing rank 127 (0-based) ----
    {
        unsigned int s = 0;
        #pragma unroll
        for (int q = 0; q < 8; ++q) s += hist[t * 8 + q];
        seg[t] = s;
        __syncthreads();
        for (int off = 1; off < 256; off <<= 1) {
            unsigned int v = seg[t];
            unsigned int u = (t >= off) ? seg[t - off] : 0;
            __syncthreads();
            seg[t] = v + u;
            __syncthreads();
        }
        unsigned int before = (t == 0) ? 0u : seg[t - 1];
        unsigned int incl = seg[t];
        if (before <= 127u && 127u < incl) {
            unsigned int c = before;
            for (int q = 0; q < 8; ++q) {
                unsigned int h = hist[t * 8 + q];
                if (c + h > 127u) { s_b1 = t * 8 + q; s_c0 = c; break; }
                c += h;
            }
        }
    }
    __syncthreads();
    unsigned int B1 = s_b1, c0 = s_c0;
    // ---- pass 2: refine within B1 on bits[19:9] ----
    for (int i = t; i < HBINS; i += 256) hist[i] = 0;
    __syncthreads();
    for (int j = t; j < NPTS; j += 256) {
        unsigned int bits = dbits[j];
        if ((bits >> 20) == B1) atomicAdd(&hist[(bits >> 9) & 0x7FFu], 1u);
    }
    __syncthreads();
    {
        unsigned int target = 127u - c0;
        unsigned int s = 0;
        #pragma unroll
        for (int q = 0; q < 8; ++q) s += hist[t * 8 + q];
        seg[t] = s;
        __syncthreads();
        for (int off = 1; off < 256; off <<= 1) {
            unsigned int v = seg[t];
            unsigned int u = (t >= off) ? seg[t - off] : 0;
            __syncthreads();
            seg[t] = v + u;
            __syncthreads();
        }
        unsigned int before = (t == 0) ? 0u : seg[t - 1];
        unsigned int incl = seg[t];
        if (before <= target && target < incl) {
            unsigned int c = before;
            for (int q = 0; q < 8; ++q) {
                unsigned int h = hist[t * 8 + q];
                if (c + h > target) { s_p22 = (B1 << 11) | (unsigned)(t * 8 + q); break; }
                c += h;
            }
        }
    }
    cand[t] = 0xFFFFFFFFFFFFFFFFull;
    __syncthreads();
    unsigned int P22 = s_p22;
    // ---- collect candidates: prefix22 <= P22 (top-128 provably contained) ----
    for (int j = t; j < NPTS; j += 256) {
        unsigned int bits = dbits[j];
        if ((bits >> 9) <= P22) {
            unsigned int pos_ = atomicAdd(&s_cnt, 1u);
            if (pos_ < 256u) cand[pos_] = ((unsigned long long)bits << 32) | (unsigned int)j;
        }
    }
    __syncthreads();
    // ---- bitonic sort 256 (ascending (dist,idx)) ----
    for (int k2 = 2; k2 <= 256; k2 <<= 1) {
        for (int s2 = k2 >> 1; s2 > 0; s2 >>= 1) {
            int l = t ^ s2;
            if (l > t) {
                unsigned long long a = cand[t], c = cand[l];
                bool up = ((t & k2) == 0);
                if ((a > c) == up) { cand[t] = c; cand[l] = a; }
            }
            __syncthreads();
        }
    }
    if (t < KNN) {
        unsigned int j = (unsigned int)(cand[t] & 0xffffffffu);
        out[FEAT_ELEMS + (size_t)blk * KNN + t] = (float)j;
        float gx_ = px[j] - qx, gy_ = py[j] - qy, gz_ = pz[j] - qz;
        gsx[t] = gx_; gsy[t] = gy_; gsz[t] = gz_;
        float* g = gp + ((size_t)blk * KNN + t) * 3;
        g[0] = gx_; g[1] = gy_; g[2] = gz_;
    }
    __syncthreads();
    // BN1 moments
    int c = t & (C1 - 1);
    int half = t >> 7;
    float wa = w1[c * 3 + 0], wb = w1[c * 3 + 1], wc = w1[c * 3 + 2], bc = b1[c];
    float s = 0.f, q = 0.f;
    for (int r = half * 64; r < half * 64 + 64; ++r) {
        float f = wa * gsx[r] + wb * gsy[r] + wc * gsz[r] + bc;
        s += f; q += f * f;
    }
    red[t] = s; __syncthreads();
    int rep = blk & (NREP - 1);
    if (t < C1) atomicAdd(bn1sumr + rep * C1 + t, red[t] + red[t + C1]);
    __syncthreads();
    red[t] = q; __syncthreads();
    if (t < C1) atomicAdd(bn1sqr + rep * C1 + t, red[t] + red[t + C1]);
}

// ---------------------------------------------------------------------------
__global__ void bn_finalize(const float* __restrict__ sumr, const float* __restrict__ sqr,
                            const float* __restrict__ g, const float* __restrict__ be,
                            float* __restrict__ scale, float* __restrict__ shift,
                            int nch, float inv_count) {
    int c = blockIdx.x * blockDim.x + threadIdx.x;
    if (c < nch) {
        float s = 0.f, q = 0.f;
        for (int r = 0; r < NREP; ++r) { s += sumr[r * nch + c]; q += sqr[r * nch + c]; }
        float m = s * inv_count;
        float v = fmaxf(q * inv_count - m * m, 0.f);
        float sc = g[c] / sqrtf(v + 1e-5f);
        scale[c] = sc;
        shift[c] = be[c] - m * sc;
    }
}

// ---------------------------------------------------------------------------
__launch_bounds__(256)
__global__ void stats2_kernel(const float* __restrict__ gp,
                              const float* __restrict__ w1, const float* __restrict__ b1,
                              const float* __restrict__ sc1, const float* __restrict__ sh1,
                              const float* __restrict__ w2t, const float* __restrict__ b2,
                              const float* __restrict__ w3t, const float* __restrict__ b3,
                              float* __restrict__ fgout,
                              float* __restrict__ bn2sumr, float* __restrict__ bn2sqr) {
    __shared__ float gfl[KNN * 3];
    __shared__ float w1s[C1 * 3], b1s[C1], sc1s[C1], sh1s[C1];
    __shared__ float h1[C1][PAD];
    __shared__ float f2s[C2][PAD];
    __shared__ float fgs[C2];
    int t = threadIdx.x, blk = blockIdx.x;
    const float* g = gp + (size_t)blk * KNN * 3;
    for (int i = t; i < KNN * 3; i += 256) gfl[i] = g[i];
    for (int i = t; i < C1 * 3; i += 256) w1s[i] = w1[i];
    if (t < C1) { b1s[t] = b1[t]; sc1s[t] = sc1[t]; sh1s[t] = sh1[t]; }
    fgs[t] = -3.4e38f;
    __syncthreads();

    float m1 = 0.f, m2 = 0.f, q1 = 0.f, q2 = 0.f;
    for (int ch = 0; ch < NCHUNK; ++ch) {
        int j0 = ch * JC;
        for (int e = t; e < C1 * JC; e += 256) {
            int cc = e >> 4, j = e & (JC - 1);
            int jj = j0 + j;
            float f = w1s[cc*3] * gfl[jj*3] + w1s[cc*3+1] * gfl[jj*3+1] + w1s[cc*3+2] * gfl[jj*3+2] + b1s[cc];
            h1[cc][j] = fmaxf(f * sc1s[cc] + sh1s[cc], 0.f);
        }
        __syncthreads();
        // conv2 (out channel t)
        float acc[JC];
        #pragma unroll
        for (int j = 0; j < JC; ++j) acc[j] = 0.f;
        for (int c1_ = 0; c1_ < C1; ++c1_) {
            float w = w2t[c1_ * C2 + t];
            const float4* hr = (const float4*)h1[c1_];
            float4 h0 = hr[0], h1v = hr[1], h2 = hr[2], h3 = hr[3];
            acc[0] += w*h0.x;  acc[1] += w*h0.y;  acc[2] += w*h0.z;  acc[3] += w*h0.w;
            acc[4] += w*h1v.x; acc[5] += w*h1v.y; acc[6] += w*h1v.z; acc[7] += w*h1v.w;
            acc[8] += w*h2.x;  acc[9] += w*h2.y;  acc[10]+= w*h2.z;  acc[11]+= w*h2.w;
            acc[12]+= w*h3.x;  acc[13]+= w*h3.y;  acc[14]+= w*h3.z;  acc[15]+= w*h3.w;
        }
        float bb = b2[t];
        float mx = -3.4e38f;
        float4* fw = (float4*)f2s[t];
        #pragma unroll
        for (int qd = 0; qd < 4; ++qd) {
            float v0 = acc[qd*4+0] + bb, v1 = acc[qd*4+1] + bb, v2 = acc[qd*4+2] + bb, v3 = acc[qd*4+3] + bb;
            fw[qd] = make_float4(v0, v1, v2, v3);
            mx = fmaxf(mx, fmaxf(fmaxf(v0, v1), fmaxf(v2, v3)));
        }
        fgs[t] = fmaxf(fgs[t], mx);
        __syncthreads();
        // conv3 partial (input channels 256..511 half), rows t and t+256
        float a0[JC], a1[JC];
        #pragma unroll
        for (int j = 0; j < JC; ++j) { a0[j] = 0.f; a1[j] = 0.f; }
        for (int c2_ = 0; c2_ < C2; ++c2_) {
            const float* wr = w3t + (size_t)(C2 + c2_) * C3;
            float wA = wr[t], wB = wr[t + 256];
            const float4* fr = (const float4*)f2s[c2_];
            float4 f0 = fr[0], f1 = fr[1], f2 = fr[2], f3 = fr[3];
            a0[0] += wA*f0.x;  a0[1] += wA*f0.y;  a0[2] += wA*f0.z;  a0[3] += wA*f0.w;
            a0[4] += wA*f1.x;  a0[5] += wA*f1.y;  a0[6] += wA*f1.z;  a0[7] += wA*f1.w;
            a0[8] += wA*f2.x;  a0[9] += wA*f2.y;  a0[10]+= wA*f2.z;  a0[11]+= wA*f2.w;
            a0[12]+= wA*f3.x;  a0[13]+= wA*f3.y;  a0[14]+= wA*f3.z;  a0[15]+= wA*f3.w;
            a1[0] += wB*f0.x;  a1[1] += wB*f0.y;  a1[2] += wB*f0.z;  a1[3] += wB*f0.w;
            a1[4] += wB*f1.x;  a1[5] += wB*f1.y;  a1[6] += wB*f1.z;  a1[7] += wB*f1.w;
            a1[8] += wB*f2.x;  a1[9] += wB*f2.y;  a1[10]+= wB*f2.z;  a1[11]+= wB*f2.w;
            a1[12]+= wB*f3.x;  a1[13]+= wB*f3.y;  a1[14]+= wB*f3.z;  a1[15]+= wB*f3.w;
        }
        #pragma unroll
        for (int j = 0; j < JC; ++j) {
            m1 += a0[j]; q1 += a0[j] * a0[j];
            m2 += a1[j]; q2 += a1[j] * a1[j];
        }
        __syncthreads();
    }
    float c3a = b3[t], c3b = b3[t + 256];
    for (int c2_ = 0; c2_ < C2; ++c2_) {
        float f = fgs[c2_];
        c3a += w3t[(size_t)c2_ * C3 + t] * f;
        c3b += w3t[(size_t)c2_ * C3 + t + 256] * f;
    }
    int rep = blk & (NREP - 1);
    atomicAdd(bn2sumr + rep * C3 + t,        m1 + 128.f * c3a);
    atomicAdd(bn2sqr  + rep * C3 + t,        q1 + 2.f * c3a * m1 + 128.f * c3a * c3a);
    atomicAdd(bn2sumr + rep * C3 + t + 256,  m2 + 128.f * c3b);
    atomicAdd(bn2sqr  + rep * C3 + t + 256,  q2 + 2.f * c3b * m2 + 128.f * c3b * c3b);
    fgout[(size_t)blk * C2 + t] = fgs[t];
}

// ---------------------------------------------------------------------------
__launch_bounds__(256)
__global__ void final_kernel(const float* __restrict__ gp,
                             const float* __restrict__ w1, const float* __restrict__ b1,
                             const float* __restrict__ sc1, const float* __restrict__ sh1,
                             const float* __restrict__ w2t, const float* __restrict__ b2,
                             const float* __restrict__ w3t, const float* __restrict__ b3,
                             const float* __restrict__ sc2, const float* __restrict__ sh2,
                             const float* __restrict__ w4t, const float* __restrict__ b4,
                             const float* __restrict__ fgin, float* __restrict__ out) {
    __shared__ float gfl[KNN * 3];
    __shared__ float w1s[C1 * 3], b1s[C1], sc1s[C1], sh1s[C1];
    __shared__ float sc2s[C3], sh2s[C3], c3s[C3];
    __shared__ float fgs[C2];
    __shared__ float f2s[C2][PAD];
    __shared__ float g3[C3][PAD];
    float (*h1)[PAD] = g3;

    int t = threadIdx.x, blk = blockIdx.x;
    const float* g = gp + (size_t)blk * KNN * 3;
    for (int i = t; i < KNN * 3; i += 256) gfl[i] = g[i];
    for (int i = t; i < C1 * 3; i += 256) w1s[i] = w1[i];
    if (t < C1) { b1s[t] = b1[t]; sc1s[t] = sc1[t]; sh1s[t] = sh1[t]; }
    for (int i = t; i < C3; i += 256) { sc2s[i] = sc2[i]; sh2s[i] = sh2[i]; }
    fgs[t] = fgin[(size_t)blk * C2 + t];
    __syncthreads();
    {
        float c3a = b3[t], c3b = b3[t + 256];
        for (int c2_ = 0; c2_ < C2; ++c2_) {
            float f = fgs[c2_];
            c3a += w3t[(size_t)c2_ * C3 + t] * f;
            c3b += w3t[(size_t)c2_ * C3 + t + 256] * f;
        }
        c3s[t] = c3a; c3s[t + 256] = c3b;
    }
    __syncthreads();

    int c4 = t & (C4 - 1), jh = t >> 7;
    float fm = -3.4e38f;
    for (int ch = 0; ch < NCHUNK; ++ch) {
        int j0 = ch * JC;
        for (int e = t; e < C1 * JC; e += 256) {
            int cc = e >> 4, j = e & (JC - 1);
            int jj = j0 + j;
            float f = w1s[cc*3] * gfl[jj*3] + w1s[cc*3+1] * gfl[jj*3+1] + w1s[cc*3+2] * gfl[jj*3+2] + b1s[cc];
            h1[cc][j] = fmaxf(f * sc1s[cc] + sh1s[cc], 0.f);
        }
        __syncthreads();
        float acc[JC];
        #pragma unroll
        for (int j = 0; j < JC; ++j) acc[j] = 0.f;
        for (int c1_ = 0; c1_ < C1; ++c1_) {
            float w = w2t[c1_ * C2 + t];
            const float4* hr = (const float4*)h1[c1_];
            float4 h0 = hr[0], h1v = hr[1], h2 = hr[2], h3 = hr[3];
            acc[0] += w*h0.x;  acc[1] += w*h0.y;  acc[2] += w*h0.z;  acc[3] += w*h0.w;
            acc[4] += w*h1v.x; acc[5] += w*h1v.y; acc[6] += w*h1v.z; acc[7] += w*h1v.w;
            acc[8] += w*h2.x;  acc[9] += w*h2.y;  acc[10]+= w*h2.z;  acc[11]+= w*h2.w;
            acc[12]+= w*h3.x;  acc[13]+= w*h3.y;  acc[14]+= w*h3.z;  acc[15]+= w*h3.w;
        }
        float bb = b2[t];
        __syncthreads();   // h1 (aliasing g3) fully consumed before f2s fill & g3 overwrite
        float4* fw = (float4*)f2s[t];
        #pragma unroll
        for (int qd = 0; qd < 4; ++qd)
            fw[qd] = make_float4(acc[qd*4+0] + bb, acc[qd*4+1] + bb, acc[qd*4+2] + bb, acc[qd*4+3] + bb);
        __syncthreads();
        float a0[JC], a1[JC];
        #pragma unroll
        for (int j = 0; j < JC; ++j) { a0[j] = 0.f; a1[j] = 0.f; }
        for (int c2_ = 0; c2_ < C2; ++c2_) {
            const float* wr = w3t + (size_t)(C2 + c2_) * C3;
            float wA = wr[t], wB = wr[t + 256];
            const float4* fr = (const float4*)f2s[c2_];
            float4 f0 = fr[0], f1 = fr[1], f2 = fr[2], f3 = fr[3];
            a0[0] += wA*f0.x;  a0[1] += wA*f0.y;  a0[2] += wA*f0.z;  a0[3] += wA*f0.w;
            a0[4] += wA*f1.x;  a0[5] += wA*f1.y;  a0[6] += wA*f1.z;  a0[7] += wA*f1.w;
            a0[8] += wA*f2.x;  a0[9] += wA*f2.y;  a0[10]+= wA*f2.z;  a0[11]+= wA*f2.w;
            a0[12]+= wA*f3.x;  a0[13]+= wA*f3.y;  a0[14]+= wA*f3.z;  a0[15]+= wA*f3.w;
            a1[0] += wB*f0.x;  a1[1] += wB*f0.y;  a1[2] += wB*f0.z;  a1[3] += wB*f0.w;
            a1[4] += wB*f1.x;  a1[5] += wB*f1.y;  a1[6] += wB*f1.z;  a1[7] += wB*f1.w;
            a1[8] += wB*f2.x;  a1[9] += wB*f2.y;  a1[10]+= wB*f2.z;  a1[11]+= wB*f2.w;
            a1[12]+= wB*f3.x;  a1[13]+= wB*f3.y;  a1[14]+= wB*f3.z;  a1[15]+= wB*f3.w;
        }
        float sA = sc2s[t], hA = sh2s[t], cA = c3s[t];
        float sB = sc2s[t + 256], hB = sh2s[t + 256], cB = c3s[t + 256];
        float4* g0 = (float4*)g3[t];
        float4* g1 = (float4*)g3[t + 256];
        #pragma unroll
        for (int qd = 0; qd < 4; ++qd) {
            g0[qd] = make_float4(fmaxf((a0[qd*4+0]+cA)*sA+hA, 0.f), fmaxf((a0[qd*4+1]+cA)*sA+hA, 0.f),
                                 fmaxf((a0[qd*4+2]+cA)*sA+hA, 0.f), fmaxf((a0[qd*4+3]+cA)*sA+hA, 0.f));
            g1[qd] = make_float4(fmaxf((a1[qd*4+0]+cB)*sB+hB, 0.f), fmaxf((a1[qd*4+1]+cB)*sB+hB, 0.f),
                                 fmaxf((a1[qd*4+2]+cB)*sB+hB, 0.f), fmaxf((a1[qd*4+3]+cB)*sB+hB, 0.f));
        }
        __syncthreads();
        float f4[8];
        #pragma unroll
        for (int jj = 0; jj < 8; ++jj) f4[jj] = 0.f;
        for (int cc = 0; cc < C3; ++cc) {
            float w = w4t[cc * C4 + c4];
            const float4* gr = (const float4*)(&g3[cc][jh * 8]);
            float4 ga = gr[0], gb = gr[1];
            f4[0] += w*ga.x; f4[1] += w*ga.y; f4[2] += w*ga.z; f4[3] += w*ga.w;
            f4[4] += w*gb.x; f4[5] += w*gb.y; f4[6] += w*gb.z; f4[7] += w*gb.w;
        }
        #pragma unroll
        for (int jj = 0; jj < 8; ++jj) fm = fmaxf(fm, f4[jj]);
        __syncthreads();
    }
    fgs[t] = fm;
    __syncthreads();
    if (t < C4) {
        float v = fmaxf(fgs[t], fgs[t + C4]) + b4[t];
        int b = blk >> 11, n = blk & (NPTS - 1);
        out[((size_t)b * C4 + t) * NPTS + n] = v;
    }
}

// ---------------------------------------------------------------------------
extern "C" void kernel_launch(void* const* d_in, const int* in_sizes, int n_in,
                              void* d_out, int out_size, void* d_ws, size_t ws_size,
                              hipStream_t stream) {
    const float* pos = (const float*)d_in[0];
    const float* w1  = (const float*)d_in[1];
    const float* b1  = (const float*)d_in[2];
    const float* g1  = (const float*)d_in[3];
    const float* be1 = (const float*)d_in[4];
    const float* w2  = (const float*)d_in[5];
    const float* b2  = (const float*)d_in[6];
    const float* w3  = (const float*)d_in[7];
    const float* b3  = (const float*)d_in[8];
    const float* g2  = (const float*)d_in[9];
    const float* be2 = (const float*)d_in[10];
    const float* w4  = (const float*)d_in[11];
    const float* b4  = (const float*)d_in[12];
    float* out = (float*)d_out;
    float* ws  = (float*)d_ws;

    float* gp      = ws;                          // 1572864
    float* w2t     = gp + 1572864;                // 32768
    float* w3t     = w2t + 32768;                 // 262144
    float* w4t     = w3t + 262144;                // 65536
    float* bn1sumr = w4t + 65536;                 // 8*128 = 1024
    float* bn1sqr  = bn1sumr + NREP * C1;         // 1024
    float* bn2sumr = bn1sqr + NREP * C1;          // 8*512 = 4096
    float* bn2sqr  = bn2sumr + NREP * C3;         // 4096
    float* sc1     = bn2sqr + NREP * C3;          // 128
    float* sh1     = sc1 + 128;                   // 128
    float* sc2     = sh1 + 128;                   // 512
    float* sh2     = sc2 + 512;                   // 512
    float* fg      = sh2 + 512;                   // 1048576

    hipMemsetAsync(bn1sumr, 0, (size_t)(2 * NREP * C1 + 2 * NREP * C3) * sizeof(float), stream);
    prep_kernel<<<512, 256, 0, stream>>>(w2, w3, w4, w2t, w3t, w4t);
    knn_kernel<<<NGROUP, 256, 0, stream>>>(pos, w1, b1, out, gp, bn1sumr, bn1sqr);
    bn_finalize<<<1, 128, 0, stream>>>(bn1sumr, bn1sqr, g1, be1, sc1, sh1, C1, 1.f / 524288.f);
    stats2_kernel<<<NGROUP, 256, 0, stream>>>(gp, w1, b1, sc1, sh1, w2t, b2, w3t, b3,
                                              fg, bn2sumr, bn2sqr);
    bn_finalize<<<1, 512, 0, stream>>>(bn2sumr, bn2sqr, g2, be2, sc2, sh2, C3, 1.f / 524288.f);
    final_kernel<<<NGROUP, 256, 0, stream>>>(gp, w1, b1, sc1, sh1, w2t, b2, w3t, b3,
                                             sc2, sh2, w4t, b4, fg, out);
}